// Round 3
// baseline (751.680 us; speedup 1.0000x reference)
//
#include <hip/hip_runtime.h>

#define TV 32
#define TT 8192
#define TL 16
#define NCHAIN (TV * TL)        // 512 chains
#define CHUNK 16
#define NCHUNK (TT / CHUNK)     // 512
#define NE ((size_t)NCHUNK * NCHAIN)   // 262144 (chunk,chain) records
#define JIT 1e-6f
#define SQ3 1.7320508075688772f
#define C_LOG2PI 1.837877066409345483560659472811f
#define SB 8

// ===========================================================================
// Exact chunked Kalman pipeline (no warm-up anywhere):
//   f1:    per-chunk filtering element (A,b,C,eta,J)  [Sarkka parallel filter]
//   scanF: sequential prefix-apply per chain -> exact chunk-incoming posterior
//   f2:    real filter, 16 steps/thread, outputs m_fs/P_fs/slp + smoother maps
//   scanB: sequential suffix-apply of smoother maps -> incoming smoothed state
//   bwd:   apply-only RTS smoother, 16 steps/thread
// CHUNK=16 -> 262144 threads -> 4 waves/SIMD (prev: 2). waves_per_eu(4) caps
// VGPR at 128 so occupancy is realized.
// ===========================================================================

// ---------------------------------------------------------------------------
// f1: compose the filtering element of each chunk (steps t=s..s+15).
// Step element (H=[1,0], obs var r, transition A,Q):
//   S=q00+r; K=[q00,q01]/S; A_e=(I-KH)A; b=Ky; C_e=(I-KH)Q;
//   eta=[a11,a12]*y/S; J=[a11,a12]^T[a11,a12]/S.
// Compose (L earlier, R later), M = I + C_L J_R, N = M^-1:
//   A=A_R N A_L; b=A_R N (b_L + C_L eta_R) + b_R; C=A_R N C_L A_R^T + C_R;
//   eta=A_L^T N^T (eta_R - J_R b_L) + eta_L; J=A_L^T N^T J_R A_L + J_L.
// ---------------------------------------------------------------------------
__global__ void __launch_bounds__(256) __attribute__((amdgpu_waves_per_eu(4)))
kf_f1(const float* __restrict__ dt, const float* __restrict__ y,
      const float* __restrict__ rvar, const float* __restrict__ ls,
      const float* __restrict__ var,
      float4* __restrict__ eA,   // (k,chain) A
      float4* __restrict__ eC,   // c00,c01,c11,b0
      float4* __restrict__ eJ,   // j00,j01,j11,b1
      float2* __restrict__ eH)   // eta
{
    const int tid   = blockIdx.x * 256 + threadIdx.x;
    const int chain = tid & (NCHAIN - 1);
    const int k     = tid >> 9;
    const int v = chain >> 4;
    const int l = chain & 15;

    const float lam = SQ3 / ls[l];
    const float v0  = var[l];
    const float v1  = v0 * lam * lam;
    const int s = k * CHUNK;

    const float* dtv = dt + (size_t)v * (TT - 1);
    const float* yp  = y    + (size_t)v * TT * TL + l;
    const float* rp  = rvar + (size_t)v * TT * TL + l;

    float yb[CHUNK], rb[CHUNK], db[CHUNK];
#pragma unroll
    for (int j = 0; j < CHUNK; ++j) {
        const int tt = s + j;
        yb[j] = yp[(size_t)tt * TL];
        rb[j] = rp[(size_t)tt * TL];
        db[j] = dtv[(tt >= 1) ? (tt - 1) : 0];
    }
    __builtin_amdgcn_sched_barrier(0);

    // running element
    float rA00, rA01, rA10, rA11, rb0, rb1;
    float rC00, rC01, rC11, rE0, rE1, rJ00, rJ01, rJ11;

#pragma unroll
    for (int j = 0; j < CHUNK; ++j) {
        const int tt = s + j;
        const float dtc = (tt == 0) ? 0.f : db[j];
        const float ldt = dtc * lam;
        const float ee  = __expf(-ldt);
        const float a11 = ee * (ldt + 1.f);
        const float a12 = ee * dtc;
        const float a21 = -ee * lam * ldt;
        const float a22 = ee * (1.f - ldt);
        const float q00 = v0 - (a11 * a11 * v0 + a12 * a12 * v1);
        const float q01 = -(a11 * a21 * v0 + a12 * a22 * v1);
        const float q11 = v1 - (a21 * a21 * v0 + a22 * a22 * v1);

        const float S    = q00 + rb[j];
        const float Sinv = __builtin_amdgcn_rcpf(S);
        const float k0 = q00 * Sinv, k1 = q01 * Sinv;
        const float o0 = 1.f - k0;
        // step element
        const float sA00 = o0 * a11,        sA01 = o0 * a12;
        const float sA10 = a21 - k1 * a11,  sA11 = a22 - k1 * a12;
        const float sb0 = k0 * yb[j],       sb1 = k1 * yb[j];
        const float sC00 = o0 * q00, sC01 = o0 * q01, sC11 = q11 - k1 * q01;
        const float ys = yb[j] * Sinv;
        const float sE0 = a11 * ys, sE1 = a12 * ys;
        const float sJ00 = a11 * a11 * Sinv;
        const float sJ01 = a11 * a12 * Sinv;
        const float sJ11 = a12 * a12 * Sinv;

        if (j == 0) {
            rA00 = sA00; rA01 = sA01; rA10 = sA10; rA11 = sA11;
            rb0 = sb0; rb1 = sb1;
            rC00 = sC00; rC01 = sC01; rC11 = sC11;
            rE0 = sE0; rE1 = sE1;
            rJ00 = sJ00; rJ01 = sJ01; rJ11 = sJ11;
        } else {
            // M = I + C_L J_R
            const float M00 = 1.f + rC00 * sJ00 + rC01 * sJ01;
            const float M01 =       rC00 * sJ01 + rC01 * sJ11;
            const float M10 =       rC01 * sJ00 + rC11 * sJ01;
            const float M11 = 1.f + rC01 * sJ01 + rC11 * sJ11;
            const float dinv = __builtin_amdgcn_rcpf(M00 * M11 - M01 * M10);
            const float N00 =  M11 * dinv, N01 = -M01 * dinv;
            const float N10 = -M10 * dinv, N11 =  M00 * dinv;
            // T = A_R N
            const float T00 = sA00 * N00 + sA01 * N10;
            const float T01 = sA00 * N01 + sA01 * N11;
            const float T10 = sA10 * N00 + sA11 * N10;
            const float T11 = sA10 * N01 + sA11 * N11;
            // U = A_L^T N^T
            const float U00 = rA00 * N00 + rA10 * N01;
            const float U01 = rA00 * N10 + rA10 * N11;
            const float U10 = rA01 * N00 + rA11 * N01;
            const float U11 = rA01 * N10 + rA11 * N11;
            // b' = T (b_L + C_L eta_R) + b_R
            const float u0 = rb0 + rC00 * sE0 + rC01 * sE1;
            const float u1 = rb1 + rC01 * sE0 + rC11 * sE1;
            const float nb0 = T00 * u0 + T01 * u1 + sb0;
            const float nb1 = T10 * u0 + T11 * u1 + sb1;
            // eta' = U (eta_R - J_R b_L) + eta_L
            const float w0 = sE0 - (sJ00 * rb0 + sJ01 * rb1);
            const float w1 = sE1 - (sJ01 * rb0 + sJ11 * rb1);
            const float nE0 = U00 * w0 + U01 * w1 + rE0;
            const float nE1 = U10 * w0 + U11 * w1 + rE1;
            // A' = T A_L
            const float nA00 = T00 * rA00 + T01 * rA10;
            const float nA01 = T00 * rA01 + T01 * rA11;
            const float nA10 = T10 * rA00 + T11 * rA10;
            const float nA11 = T10 * rA01 + T11 * rA11;
            // C' = T C_L A_R^T + C_R
            const float X00 = T00 * rC00 + T01 * rC01;
            const float X01 = T00 * rC01 + T01 * rC11;
            const float X10 = T10 * rC00 + T11 * rC01;
            const float X11 = T10 * rC01 + T11 * rC11;
            const float nC00 = X00 * sA00 + X01 * sA01 + sC00;
            const float nC01 = X00 * sA10 + X01 * sA11 + sC01;
            const float nC11 = X10 * sA10 + X11 * sA11 + sC11;
            // J' = U (J_R A_L) + J_L
            const float V00 = sJ00 * rA00 + sJ01 * rA10;
            const float V01 = sJ00 * rA01 + sJ01 * rA11;
            const float V10 = sJ01 * rA00 + sJ11 * rA10;
            const float V11 = sJ01 * rA01 + sJ11 * rA11;
            const float nJ00 = U00 * V00 + U01 * V10 + rJ00;
            const float nJ01 = U00 * V01 + U01 * V11 + rJ01;
            const float nJ11 = U10 * V01 + U11 * V11 + rJ11;

            rA00 = nA00; rA01 = nA01; rA10 = nA10; rA11 = nA11;
            rb0 = nb0; rb1 = nb1;
            rC00 = nC00; rC01 = nC01; rC11 = nC11;
            rE0 = nE0; rE1 = nE1;
            rJ00 = nJ00; rJ01 = nJ01; rJ11 = nJ11;
        }
    }

    const size_t ix = (size_t)k * NCHAIN + chain;   // coalesced
    eA[ix] = make_float4(rA00, rA01, rA10, rA11);
    eC[ix] = make_float4(rC00, rC01, rC11, rb0);
    eJ[ix] = make_float4(rJ00, rJ01, rJ11, rb1);
    eH[ix] = make_float2(rE0, rE1);
}

// ---------------------------------------------------------------------------
// scanF: per chain, prefix-apply the 512 chunk elements to the prior seed
// (m=0, P=diag(v0,v1)); store each chunk's incoming posterior BEFORE applying.
// apply: M=I+P J; N=M^-1; W=A N; m'=W(m+P eta)+b; P'=W P A^T + C.
// Double-buffered 8-element prefetch.
// ---------------------------------------------------------------------------
__global__ void __launch_bounds__(256) kf_scanF(
    const float* __restrict__ ls, const float* __restrict__ var,
    const float4* __restrict__ eA, const float4* __restrict__ eC,
    const float4* __restrict__ eJ, const float2* __restrict__ eH,
    float2* __restrict__ xmF, float4* __restrict__ xPF)
{
    const int c = blockIdx.x * 256 + threadIdx.x;   // chain
    const int l = c & 15;
    const float lam = SQ3 / ls[l];
    const float v0 = var[l];
    const float v1 = v0 * lam * lam;

    float m0 = 0.f, m1 = 0.f;
    float P00 = v0, P01 = 0.f, P11 = v1;

    float4 Aa[SB], Ca[SB], Ja[SB]; float2 Ha[SB];
    float4 Ab[SB], Cb[SB], Jb[SB]; float2 Hb[SB];

#define SFLOAD(A_, C_, J_, H_, kb) {                                          \
    _Pragma("unroll")                                                         \
    for (int j = 0; j < SB; ++j) {                                            \
        const size_t ix = (size_t)((kb) + j) * NCHAIN + c;                    \
        A_[j] = eA[ix]; C_[j] = eC[ix]; J_[j] = eJ[ix]; H_[j] = eH[ix];       \
    }                                                                         \
}

#define SFAPPLY(A_, C_, J_, H_, kb) {                                         \
    _Pragma("unroll")                                                         \
    for (int j = 0; j < SB; ++j) {                                            \
        const size_t ix = (size_t)((kb) + j) * NCHAIN + c;                    \
        xmF[ix] = make_float2(m0, m1);                                        \
        xPF[ix] = make_float4(P00, P01, P11, 0.f);                            \
        const float4 A = A_[j]; const float4 C = C_[j];                       \
        const float4 J = J_[j]; const float2 H = H_[j];                       \
        const float M00 = 1.f + P00 * J.x + P01 * J.y;                        \
        const float M01 =       P00 * J.y + P01 * J.z;                        \
        const float M10 =       P01 * J.x + P11 * J.y;                        \
        const float M11 = 1.f + P01 * J.y + P11 * J.z;                        \
        const float dinv = __builtin_amdgcn_rcpf(M00 * M11 - M01 * M10);      \
        const float N00 =  M11 * dinv, N01 = -M01 * dinv;                     \
        const float N10 = -M10 * dinv, N11 =  M00 * dinv;                     \
        const float W00 = A.x * N00 + A.y * N10;                              \
        const float W01 = A.x * N01 + A.y * N11;                              \
        const float W10 = A.z * N00 + A.w * N10;                              \
        const float W11 = A.z * N01 + A.w * N11;                              \
        const float u0 = m0 + P00 * H.x + P01 * H.y;                          \
        const float u1 = m1 + P01 * H.x + P11 * H.y;                          \
        const float nm0 = W00 * u0 + W01 * u1 + C.w;   /* b0 */               \
        const float nm1 = W10 * u0 + W11 * u1 + J.w;   /* b1 */               \
        const float X00 = W00 * P00 + W01 * P01;                              \
        const float X01 = W00 * P01 + W01 * P11;                              \
        const float X10 = W10 * P00 + W11 * P01;                              \
        const float X11 = W10 * P01 + W11 * P11;                              \
        P00 = X00 * A.x + X01 * A.y + C.x;                                    \
        P01 = X00 * A.z + X01 * A.w + C.y;                                    \
        P11 = X10 * A.z + X11 * A.w + C.z;                                    \
        m0 = nm0; m1 = nm1;                                                   \
    }                                                                         \
}

    SFLOAD(Aa, Ca, Ja, Ha, 0);
    __builtin_amdgcn_sched_barrier(0);
    for (int kb = 0; kb < NCHUNK; kb += 2 * SB) {
        SFLOAD(Ab, Cb, Jb, Hb, kb + SB);
        __builtin_amdgcn_sched_barrier(0);
        SFAPPLY(Aa, Ca, Ja, Ha, kb);
        if (kb + 2 * SB < NCHUNK) {
            SFLOAD(Aa, Ca, Ja, Ha, kb + 2 * SB);
            __builtin_amdgcn_sched_barrier(0);
        }
        SFAPPLY(Ab, Cb, Jb, Hb, kb + SB);
    }
}

// ---------------------------------------------------------------------------
// f2: real filter from the exact incoming posterior; 16 steps/thread.
// Emits m_fs, P_fs, loglik, and the chunk's composed smoother map
//   Ps_s = ME + (-1)^n * Gam X Gam^T  (sign of the n-th composed step = (-1)^n)
// ---------------------------------------------------------------------------
__global__ void __launch_bounds__(256) __attribute__((amdgpu_waves_per_eu(4)))
kf_f2(const float* __restrict__ dt, const float* __restrict__ y,
      const float* __restrict__ rvar, const float* __restrict__ ls,
      const float* __restrict__ var,
      const float2* __restrict__ xmF, const float4* __restrict__ xPF,
      float* __restrict__ m_fs, float* __restrict__ P_fs,
      float* __restrict__ slp,
      float4* __restrict__ g4w, float2* __restrict__ b2w,
      float4* __restrict__ e4w)
{
    const int tid   = blockIdx.x * 256 + threadIdx.x;
    const int chain = tid & (NCHAIN - 1);
    const int k     = tid >> 9;
    const int v = chain >> 4;
    const int l = chain & 15;

    const float lam = SQ3 / ls[l];
    const float v0  = var[l];
    const float v1  = v0 * lam * lam;
    const int s = k * CHUNK;

    const float* dtv = dt + (size_t)v * (TT - 1);
    const float* yp  = y    + (size_t)v * TT * TL + l;
    const float* rp  = rvar + (size_t)v * TT * TL + l;
    float4* mo4 = (float4*)(m_fs + (size_t)chain * TT * 2);  // [t>>1]
    float4* Po  = (float4*)(P_fs + (size_t)chain * TT * 4);

    const size_t mix = (size_t)k * NCHAIN + chain;
    const float2 bm = xmF[mix];
    const float4 bP = xPF[mix];
    float m0 = bm.x, m1 = bm.y;
    float P00 = bP.x, P01 = bP.y, P11 = bP.z;

    float yb[CHUNK], rb[CHUNK], db[CHUNK];
#pragma unroll
    for (int j = 0; j < CHUNK; ++j) {
        const int tt = s + j;
        yb[j] = yp[(size_t)tt * TL];
        rb[j] = rp[(size_t)tt * TL];
        db[j] = dtv[(tt >= 1) ? (tt - 1) : 0];
    }
    __builtin_amdgcn_sched_barrier(0);

    float acc = 0.f, bm0 = 0.f, bm1 = 0.f;
    float gam00 = 1.f, gam01 = 0.f, gam10 = 0.f, gam11 = 1.f;
    float mbc0 = 0.f, mbc1 = 0.f;
    float me00 = 0.f, me01 = 0.f, me11 = 0.f;

    // compose smoother step using pre-update (m,P)=Pf_t and mp/ap/pp of t->t+1
    auto smcomp = [&](float sgn, float mp0, float mp1,
                      float ap00, float ap01, float ap10, float ap11,
                      float pp00, float pp01, float pp11) {
        const float M00_ = pp00 + JIT, M11_ = pp11 + JIT;
        const float dinv_ = __builtin_amdgcn_rcpf(M00_ * M11_ - pp01 * pp01);
        const float g00 = (M11_ * ap00 - pp01 * ap10) * dinv_;
        const float g01 = (-pp01 * ap00 + M00_ * ap10) * dinv_;
        const float g10 = (M11_ * ap01 - pp01 * ap11) * dinv_;
        const float g11 = (-pp01 * ap01 + M00_ * ap11) * dinv_;
        const float bb0 = m0 - (g00 * mp0 + g01 * mp1);
        const float bb1 = m1 - (g10 * mp0 + g11 * mp1);
        const float gp00 = g00 * pp00 + g01 * pp01;
        const float gp01 = g00 * pp01 + g01 * pp11;
        const float gp10 = g10 * pp00 + g11 * pp01;
        const float gp11 = g10 * pp01 + g11 * pp11;
        const float ee00 = P00 + (gp00 * g00 + gp01 * g01);
        const float ee01 = P01 + (gp00 * g10 + gp01 * g11);
        const float ee11 = P11 + (gp10 * g10 + gp11 * g11);
        mbc0 += gam00 * bb0 + gam01 * bb1;
        mbc1 += gam10 * bb0 + gam11 * bb1;
        const float u00 = gam00 * ee00 + gam01 * ee01;
        const float u01 = gam00 * ee01 + gam01 * ee11;
        const float u10 = gam10 * ee00 + gam11 * ee01;
        const float u11 = gam10 * ee01 + gam11 * ee11;
        me00 += sgn * (u00 * gam00 + u01 * gam01);
        me01 += sgn * (u00 * gam10 + u01 * gam11);
        me11 += sgn * (u10 * gam10 + u11 * gam11);
        const float ng00 = gam00 * g00 + gam01 * g10;
        const float ng01 = gam00 * g01 + gam01 * g11;
        const float ng10 = gam10 * g00 + gam11 * g10;
        const float ng11 = gam10 * g01 + gam11 * g11;
        gam00 = ng00; gam01 = ng01; gam10 = ng10; gam11 = ng11;
    };

#pragma unroll
    for (int j = 0; j < CHUNK; ++j) {
        const int tt = s + j;
        const float dtc = (tt == 0) ? 0.f : db[j];   // exact A=I,Q=0 at t=0
        const float ldt = dtc * lam;
        const float ee  = __expf(-ldt);
        const float a11 = ee * (ldt + 1.f);
        const float a12 = ee * dtc;
        const float a21 = -ee * lam * ldt;
        const float a22 = ee * (1.f - ldt);
        const float q00 = v0 - (a11 * a11 * v0 + a12 * a12 * v1);
        const float q01 = -(a11 * a21 * v0 + a12 * a22 * v1);
        const float q11 = v1 - (a21 * a21 * v0 + a22 * a22 * v1);

        const float mp0 = a11 * m0 + a12 * m1;
        const float mp1 = a21 * m0 + a22 * m1;
        const float ap00 = a11 * P00 + a12 * P01;
        const float ap01 = a11 * P01 + a12 * P11;
        const float ap10 = a21 * P00 + a22 * P01;
        const float ap11 = a21 * P01 + a22 * P11;
        const float pp00 = ap00 * a11 + ap01 * a12 + q00;
        const float pp01 = ap00 * a21 + ap01 * a22 + q01;
        const float pp11 = ap10 * a21 + ap11 * a22 + q11;

        // compose step t = tt-1 (skip j=0: belongs to previous chunk's epilogue)
        if (j >= 1)
            smcomp(((j & 1) != 0) ? 1.f : -1.f, mp0, mp1,
                   ap00, ap01, ap10, ap11, pp00, pp01, pp11);

        const float ssv  = pp00 + rb[j];
        const float d    = yb[j] - mp0;
        const float sinv = __builtin_amdgcn_rcpf(ssv + JIT);
        const float W0 = pp00 * sinv;
        const float W1 = pp01 * sinv;
        m0 = mp0 + W0 * d;
        m1 = mp1 + W1 * d;
        P00 = pp00 - W0 * pp00;
        P01 = pp01 - W0 * pp01;
        P11 = pp11 - W1 * pp01;

        acc += -0.5f * (d * d * __builtin_amdgcn_rcpf(ssv)
                        + __logf(ssv) + C_LOG2PI);
        if ((j & 1) == 0) { bm0 = m0; bm1 = m1; }
        else mo4[tt >> 1] = make_float4(bm0, bm1, m0, m1);
        Po[tt] = make_float4(P00, P01, P01, P11);
    }

    // epilogue: compose step t = e-1 (16th compose, 15 done -> sign MINUS).
    // Last chunk has no step T-1.
    if (k != NCHUNK - 1) {
        const float dtc = dtv[s + CHUNK - 1];
        const float ldt = dtc * lam;
        const float ee  = __expf(-ldt);
        const float a11 = ee * (ldt + 1.f);
        const float a12 = ee * dtc;
        const float a21 = -ee * lam * ldt;
        const float a22 = ee * (1.f - ldt);
        const float q00 = v0 - (a11 * a11 * v0 + a12 * a12 * v1);
        const float q01 = -(a11 * a21 * v0 + a12 * a22 * v1);
        const float q11 = v1 - (a21 * a21 * v0 + a22 * a22 * v1);
        const float mp0 = a11 * m0 + a12 * m1;
        const float mp1 = a21 * m0 + a22 * m1;
        const float ap00 = a11 * P00 + a12 * P01;
        const float ap01 = a11 * P01 + a12 * P11;
        const float ap10 = a21 * P00 + a22 * P01;
        const float ap11 = a21 * P01 + a22 * P11;
        const float pp00 = ap00 * a11 + ap01 * a12 + q00;
        const float pp01 = ap00 * a21 + ap01 * a22 + q01;
        const float pp11 = ap10 * a21 + ap11 * a22 + q11;
        smcomp(-1.f, mp0, mp1, ap00, ap01, ap10, ap11, pp00, pp01, pp11);
    }

    g4w[mix] = make_float4(gam00, gam01, gam10, gam11);
    b2w[mix] = make_float2(mbc0, mbc1);
    e4w[mix] = make_float4(me00, me01, me11, 0.f);

    for (int mask = 8; mask >= 1; mask >>= 1)
        acc += __shfl_xor(acc, mask, 16);
    if ((threadIdx.x & 15) == 0)
        atomicAdd(&slp[v], acc);
}

// ---------------------------------------------------------------------------
// scanB: suffix-apply of the smoother chunk maps from the exact terminal
// state. X-coefficient sign = (-1)^{#composed steps}: + for 16-step chunks,
// - for the last chunk (15 steps). Double-buffered prefetch.
// ---------------------------------------------------------------------------
__global__ void __launch_bounds__(256) kf_scanB(
    const float* __restrict__ m_fs, const float* __restrict__ P_fs,
    const float4* __restrict__ g4w, const float2* __restrict__ b2w,
    const float4* __restrict__ e4w,
    float2* __restrict__ xmw, float4* __restrict__ xPw)
{
    const int c = blockIdx.x * 256 + threadIdx.x;   // chain
    const float* mt = m_fs + ((size_t)c * TT + (TT - 1)) * 2;
    const float* Pt = P_fs + ((size_t)c * TT + (TT - 1)) * 4;
    float xm0 = mt[0], xm1 = mt[1];
    float XP00 = Pt[0], XP01 = Pt[1], XP11 = Pt[3];

    float4 Ga[SB]; float2 Ba[SB]; float4 Ea[SB];
    float4 Gb[SB]; float2 Bb[SB]; float4 Eb[SB];

#define SBLOAD(G_, B_, E_, kb) {                                              \
    _Pragma("unroll")                                                         \
    for (int j = 0; j < SB; ++j) {                                            \
        const size_t ix = (size_t)((kb) - j) * NCHAIN + c;                    \
        G_[j] = g4w[ix]; B_[j] = b2w[ix]; E_[j] = e4w[ix];                    \
    }                                                                         \
}

#define SBAPPLY(G_, B_, E_, kb) {                                             \
    _Pragma("unroll")                                                         \
    for (int j = 0; j < SB; ++j) {                                            \
        const int k = (kb) - j;                                               \
        const size_t ix = (size_t)k * NCHAIN + c;                             \
        xmw[ix] = make_float2(xm0, xm1);                                      \
        xPw[ix] = make_float4(XP00, XP01, XP11, 0.f);                         \
        const float4 G = G_[j]; const float2 B = B_[j]; const float4 E = E_[j];\
        const float nm0 = B.x + G.x * xm0 + G.y * xm1;                        \
        const float nm1 = B.y + G.z * xm0 + G.w * xm1;                        \
        const float u00 = G.x * XP00 + G.y * XP01;                            \
        const float u01 = G.x * XP01 + G.y * XP11;                            \
        const float u10 = G.z * XP00 + G.w * XP01;                            \
        const float u11 = G.z * XP01 + G.w * XP11;                            \
        const float r00 = u00 * G.x + u01 * G.y;                              \
        const float r01 = u00 * G.z + u01 * G.w;                              \
        const float r11 = u10 * G.z + u11 * G.w;                              \
        xm0 = nm0; xm1 = nm1;                                                 \
        if (k == NCHUNK - 1) { XP00 = E.x - r00; XP01 = E.y - r01; XP11 = E.z - r11; } \
        else                 { XP00 = E.x + r00; XP01 = E.y + r01; XP11 = E.z + r11; } \
    }                                                                         \
}

    SBLOAD(Ga, Ba, Ea, NCHUNK - 1);
    __builtin_amdgcn_sched_barrier(0);
    for (int kb = NCHUNK - 1; kb >= 0; kb -= 2 * SB) {
        SBLOAD(Gb, Bb, Eb, kb - SB);
        __builtin_amdgcn_sched_barrier(0);
        SBAPPLY(Ga, Ba, Ea, kb);
        if (kb - 2 * SB >= 0) {
            SBLOAD(Ga, Ba, Ea, kb - 2 * SB);
            __builtin_amdgcn_sched_barrier(0);
        }
        SBAPPLY(Gb, Bb, Eb, kb - SB);
    }
}

// ---------------------------------------------------------------------------
// bwd: apply-only RTS smoother, 16 steps/thread, exact incoming state.
// Single-buffered 8-step batches (4 waves/SIMD hide the batch latency).
// ---------------------------------------------------------------------------
#define BB 8

__global__ void __launch_bounds__(256) __attribute__((amdgpu_waves_per_eu(4)))
kf_bwd(const float* __restrict__ dt, const float* __restrict__ ls,
       const float* __restrict__ var,
       const float* __restrict__ m_fs, const float* __restrict__ P_fs,
       const float2* __restrict__ xmw, const float4* __restrict__ xPw,
       float* __restrict__ mZ, float* __restrict__ PZ)
{
    const int tid   = blockIdx.x * 256 + threadIdx.x;
    const int chain = tid & (NCHAIN - 1);
    const int k     = tid >> 9;
    const int v = chain >> 4;
    const int l = chain & 15;

    const float lam = SQ3 / ls[l];
    const float v0  = var[l];
    const float v1  = v0 * lam * lam;

    const int s = k * CHUNK;
    const int e = s + CHUNK;

    const float* dtv = dt + (size_t)v * (TT - 1);
    const float2* mi  = (const float2*)(m_fs + (size_t)chain * TT * 2);
    const float4* mi4 = (const float4*)(m_fs + (size_t)chain * TT * 2);
    const float4* Pi  = (const float4*)(P_fs + (size_t)chain * TT * 4);
    float* mo = mZ + (size_t)chain * TT;
    float* Po = PZ + (size_t)chain * TT;

    const size_t mix = (size_t)k * NCHAIN + chain;
    const float2 x2 = xmw[mix];
    const float4 xq = xPw[mix];
    float ms0 = x2.x, ms1 = x2.y;
    float Ps00 = xq.x, Ps01 = xq.y, Ps11 = xq.z;

    auto step = [&](float dtc, float mf0, float mf1,
                    float Pf00, float Pf01, float Pf11) {
        const float ldt = dtc * lam;
        const float ee  = __expf(-ldt);
        const float a11 = ee * (ldt + 1.f);
        const float a12 = ee * dtc;
        const float a21 = -ee * lam * ldt;
        const float a22 = ee * (1.f - ldt);
        const float q00 = v0 - (a11 * a11 * v0 + a12 * a12 * v1);
        const float q01 = -(a11 * a21 * v0 + a12 * a22 * v1);
        const float q11 = v1 - (a21 * a21 * v0 + a22 * a22 * v1);

        const float mp0 = a11 * mf0 + a12 * mf1;
        const float mp1 = a21 * mf0 + a22 * mf1;
        const float ap00 = a11 * Pf00 + a12 * Pf01;
        const float ap01 = a11 * Pf01 + a12 * Pf11;
        const float ap10 = a21 * Pf00 + a22 * Pf01;
        const float ap11 = a21 * Pf01 + a22 * Pf11;
        const float pp00 = ap00 * a11 + ap01 * a12 + q00;
        const float pp01 = ap00 * a21 + ap01 * a22 + q01;
        const float pp11 = ap10 * a21 + ap11 * a22 + q11;

        const float M00 = pp00 + JIT, M11 = pp11 + JIT;
        const float dinv = __builtin_amdgcn_rcpf(M00 * M11 - pp01 * pp01);
        const float G00 = (M11 * ap00 - pp01 * ap10) * dinv;
        const float G01 = (-pp01 * ap00 + M00 * ap10) * dinv;
        const float G10 = (M11 * ap01 - pp01 * ap11) * dinv;
        const float G11 = (-pp01 * ap01 + M00 * ap11) * dinv;

        const float dm0 = ms0 - mp0, dm1 = ms1 - mp1;
        const float nms0 = mf0 + G00 * dm0 + G01 * dm1;
        const float nms1 = mf1 + G10 * dm0 + G11 * dm1;
        const float D00 = Ps00 - pp00, D01 = Ps01 - pp01, D11 = Ps11 - pp11;
        const float gd00 = G00 * D00 + G01 * D01;
        const float gd01 = G00 * D01 + G01 * D11;
        const float gd10 = G10 * D00 + G11 * D01;
        const float gd11 = G10 * D01 + G11 * D11;
        ms0 = nms0; ms1 = nms1;
        Ps00 = Pf00 - (gd00 * G00 + gd01 * G01);
        Ps01 = Pf01 - (gd00 * G10 + gd01 * G11);
        Ps11 = Pf11 - (gd10 * G10 + gd11 * G11);
    };

    int t;
    if (k == NCHUNK - 1) {
        mo[TT - 1] = ms0;            // terminal output = incoming state
        Po[TT - 1] = Ps00;
        t = TT - 2;
    } else {
        t = e - 1;                   // == 16k+15, t&7 == 7 -> no peel
    }

    for (; t >= s && (t & 7) != 7; --t) {
        const float2 mf2 = mi[t];
        const float4 Pf4 = Pi[t];
        step(dtv[t], mf2.x, mf2.y, Pf4.x, Pf4.y, Pf4.w);
        mo[t] = ms0; Po[t] = Ps00;
    }

    float b0m = 0.f, b1m = 0.f, b2m = 0.f, b3m = 0.f;
    float b0P = 0.f, b1P = 0.f, b2P = 0.f, b3P = 0.f;
    float4 Ma[BB / 2], Pa[BB]; float Da[BB];

    int nb = (t - s + 1) >> 3;       // 2 (k<511) or 1 (k==511)
    for (; nb > 0; --nb) {
        const int ib = (t - 7) >> 1;
#pragma unroll
        for (int j = 0; j < BB / 2; ++j) Ma[j] = mi4[ib + j];
#pragma unroll
        for (int j = 0; j < BB; ++j) {
            const int tt = t - j;
            Pa[j] = Pi[tt];
            Da[j] = dtv[tt];
        }
        __builtin_amdgcn_sched_barrier(0);
#pragma unroll
        for (int jj = 0; jj < BB; ++jj) {
            const int tt = t - jj;
            const int kk = 7 - jj;                 // ascending index in batch
            const float mf0_ = (kk & 1) ? Ma[kk >> 1].z : Ma[kk >> 1].x;
            const float mf1_ = (kk & 1) ? Ma[kk >> 1].w : Ma[kk >> 1].y;
            step(Da[jj], mf0_, mf1_, Pa[jj].x, Pa[jj].y, Pa[jj].w);
            const int slot = kk & 3;               // == tt & 3, compile-time
            if (slot == 3)      { b3m = ms0; b3P = Ps00; }
            else if (slot == 2) { b2m = ms0; b2P = Ps00; }
            else if (slot == 1) { b1m = ms0; b1P = Ps00; }
            else {
                b0m = ms0; b0P = Ps00;
                *(float4*)(mo + tt) = make_float4(b0m, b1m, b2m, b3m);
                *(float4*)(Po + tt) = make_float4(b0P, b1P, b2P, b3P);
            }
        }
        t -= BB;
    }
}

extern "C" void kernel_launch(void* const* d_in, const int* in_sizes, int n_in,
                              void* d_out, int out_size, void* d_ws, size_t ws_size,
                              hipStream_t stream) {
    const float* dt  = (const float*)d_in[0];
    const float* y   = (const float*)d_in[1];
    const float* rv  = (const float*)d_in[2];
    const float* ls  = (const float*)d_in[3];
    const float* var = (const float*)d_in[4];

    float* out  = (float*)d_out;
    float* m_fs = out;                                    // V*L*T*2
    float* P_fs = m_fs + (size_t)NCHAIN * TT * 2;         // V*L*T*4
    float* mZ   = P_fs + (size_t)NCHAIN * TT * 4;         // V*L*T
    float* PZ   = mZ + (size_t)NCHAIN * TT;               // V*L*T
    float* slp  = PZ + (size_t)NCHAIN * TT;               // V

    // Workspace (20 MB total, regions reused across pipeline stages):
    //  R1 (14 MB): filter elements (f1->scanF), then smoother maps (f2->scanB)
    //  R2 (6 MB):  incoming posteriors (scanF->f2), then smoothed states
    //              (scanB->bwd). Aliasing is safe: strictly stream-ordered.
    float* base = (float*)d_ws;
    float4* eA = (float4*)base;                  // NE * 4 floats
    float4* eC = (float4*)(base + NE * 4);
    float4* eJ = (float4*)(base + NE * 8);
    float2* eH = (float2*)(base + NE * 12);      // NE * 2
    // smoother maps alias the element region (elements dead after scanF):
    float4* g4w = (float4*)base;
    float4* e4w = (float4*)(base + NE * 4);
    float2* b2w = (float2*)(base + NE * 8);
    // R2:
    float* R2 = base + NE * 14;
    float2* xmF = (float2*)R2;                   // NE * 2
    float4* xPF = (float4*)(R2 + NE * 2);        // NE * 4
    float2* xmw = xmF;                           // alias (xF dead after f2)
    float4* xPw = xPF;

    hipMemsetAsync(slp, 0, TV * sizeof(float), stream);

    const int ntask = NCHAIN * NCHUNK;           // 262144 threads
    kf_f1<<<ntask / 256, 256, 0, stream>>>(dt, y, rv, ls, var, eA, eC, eJ, eH);
    kf_scanF<<<NCHAIN / 256, 256, 0, stream>>>(ls, var, eA, eC, eJ, eH, xmF, xPF);
    kf_f2<<<ntask / 256, 256, 0, stream>>>(dt, y, rv, ls, var, xmF, xPF,
                                           m_fs, P_fs, slp, g4w, b2w, e4w);
    kf_scanB<<<NCHAIN / 256, 256, 0, stream>>>(m_fs, P_fs, g4w, b2w, e4w, xmw, xPw);
    kf_bwd<<<ntask / 256, 256, 0, stream>>>(dt, ls, var, m_fs, P_fs, xmw, xPw, mZ, PZ);
}

// Round 4
// 336.535 us; speedup vs baseline: 2.2336x; 2.2336x over previous
//
#include <hip/hip_runtime.h>

#define TV 32
#define TT 8192
#define TL 16
#define NCHAIN (TV * TL)        // 512 chains
#define CHUNK 32
#define WARM 96
#define NCHUNK (TT / CHUNK)     // 256
#define JIT 1e-6f
#define C_LOG2PI 1.837877066409345483560659472811f
#define SB 8
#define BB 8

// element K of a float4 array, K literal
#define F4E(A, K) ((K & 3) == 0 ? A[K >> 2].x : (K & 3) == 1 ? A[K >> 2].y \
                   : (K & 3) == 2 ? A[K >> 2].z : A[K >> 2].w)

// ---------------------------------------------------------------------------
// Forward Kalman filter, chunked with warm-up from the stationary prior.
// Round-4 change: block-cooperative LDS staging of y/rvar (16-step phases,
// double-buffered 64KB tile). Per-step input reads are conflict-free
// ds_read_b32 (lgkmcnt) -> decoupled from the output stores' vmcnt; global
// staging loads are 12 coalesced float4/thread/phase, waited once per phase
// after a full compute phase of overlap. Step math and store pattern are
// identical to the round-2 build. 2 blocks/CU (LDS 64KB) = grid cap.
// ---------------------------------------------------------------------------
__global__ void __launch_bounds__(256, 2)
kf_fwd(
    const float* __restrict__ dt,    // (V, T-1)
    const float* __restrict__ y,     // (V, T, L)
    const float* __restrict__ rvar,  // (V, T, L)
    const float* __restrict__ ls,    // (L)
    const float* __restrict__ var,   // (L)
    float* __restrict__ m_fs,        // (V,L,T,2)
    float* __restrict__ P_fs,        // (V,L,T,4)
    float* __restrict__ slp,         // (V) -- pre-zeroed, atomicAdd
    float4* __restrict__ g4w,        // (NCHUNK, NCHAIN) Gamma
    float2* __restrict__ b2w,        // (NCHUNK, NCHAIN) B
    float4* __restrict__ e4w)        // (NCHUNK, NCHAIN) E (sym, .w pad)
{
    const int tx    = threadIdx.x;
    const int bb    = blockIdx.x;
    const int chain = ((bb & 1) << 8) | tx;     // == tid & 511
    const int chunk = bb >> 1;                  // == tid >> 9 (uniform/block)
    const int vb    = (bb & 1) << 4;            // block's base v
    const int v = chain >> 4;
    const int l = chain & 15;

    const float lam = 1.7320508075688772f / ls[l];
    const float pv0 = var[l];
    const float pv1 = pv0 * lam * lam;

    const int s  = chunk * CHUNK;
    const int e  = s + CHUNK;
    const int u0 = (s >= WARM) ? (s - WARM) : 0;   // multiple of 32
    const int nph = (e - u0) >> 4;                 // 2,4,6,8 -- always EVEN

    const float* dtv = dt + (size_t)v * (TT - 1);
    float4* mo4 = (float4*)(m_fs + (size_t)chain * TT * 2);  // [t>>1]
    float4* Po  = (float4*)(P_fs + (size_t)chain * TT * 4);

    // LDS tiles: [buf][trel][vl], vl = (v-vb)*16 + l == tx  (conflict-free)
    __shared__ float ylds[2][16][256];   // 32 KB
    __shared__ float rlds[2][16][256];   // 32 KB

    // staging decode (constant per thread): float4 f4idx = tx + 256*i covers
    // tile words [f4*4, f4*4+4) -> trel = wid+4i, vl = q4..q4+3
    const int wid = tx >> 6;
    const int q4  = (tx & 63) * 4;
    const int svloc = q4 >> 4;              // 0..15
    const int sl0   = q4 & 15;              // 0,4,8,12
    const float* ysrc0 = y    + (size_t)(vb + svloc) * TT * TL + sl0;
    const float* rsrc0 = rvar + (size_t)(vb + svloc) * TT * TL + sl0;

    float4 YaA[4], RaA[4], DaA[4];
    float4 YaB[4], RaB[4], DaB[4];

#define PLOAD(YA, RA, DA, T0S) {                                              \
    _Pragma("unroll")                                                         \
    for (int i = 0; i < 4; ++i) {                                             \
        const int trel = wid + 4 * i;                                         \
        YA[i] = *(const float4*)(ysrc0 + (size_t)((T0S) + trel) * TL);        \
        RA[i] = *(const float4*)(rsrc0 + (size_t)((T0S) + trel) * TL);        \
        DA[i] = *(const float4*)(dtv + (T0S) + 4 * i);                        \
    }                                                                         \
    __builtin_amdgcn_sched_barrier(0);                                        \
}

#define PWRITE(NB, YA, RA) {                                                  \
    _Pragma("unroll")                                                         \
    for (int i = 0; i < 4; ++i) {                                             \
        ((float4*)&ylds[NB][0][0])[tx + 256 * i] = YA[i];                     \
        ((float4*)&rlds[NB][0][0])[tx + 256 * i] = RA[i];                     \
    }                                                                         \
}

    float m0 = 0.f, m1 = 0.f;
    float P00 = pv0, P01 = 0.f, P11 = pv1;
    float acc = 0.f;
    float bm0 = 0.f, bm1 = 0.f;
    float dprev = (u0 > 0) ? dtv[u0 - 1] : 0.f;   // dt feeding step tt=t0

    // composed smoother map of this chunk (identity init)
    float gam00 = 1.f, gam01 = 0.f, gam10 = 0.f, gam11 = 1.f;
    float mbc0 = 0.f, mbc1 = 0.f;
    float me00 = 0.f, me01 = 0.f, me11 = 0.f;

// compose one smoother step t = tt-1 into the running map (round-2 verbatim).
#define MAPCOMPOSE(SGNPLUS)                                                   \
    {                                                                         \
        const float M00_ = pp00 + JIT, M11_ = pp11 + JIT;                     \
        const float dinv_ = __builtin_amdgcn_rcpf(M00_ * M11_ - pp01 * pp01); \
        const float g00 = (M11_ * ap00 - pp01 * ap10) * dinv_;                \
        const float g01 = (-pp01 * ap00 + M00_ * ap10) * dinv_;               \
        const float g10 = (M11_ * ap01 - pp01 * ap11) * dinv_;                \
        const float g11 = (-pp01 * ap01 + M00_ * ap11) * dinv_;               \
        const float bb0 = m0 - (g00 * mp0 + g01 * mp1);                       \
        const float bb1 = m1 - (g10 * mp0 + g11 * mp1);                       \
        const float gp00 = g00 * pp00 + g01 * pp01;                           \
        const float gp01 = g00 * pp01 + g01 * pp11;                           \
        const float gp10 = g10 * pp00 + g11 * pp01;                           \
        const float gp11 = g10 * pp01 + g11 * pp11;                           \
        const float ee00 = P00 + (gp00 * g00 + gp01 * g01);                   \
        const float ee01 = P01 + (gp00 * g10 + gp01 * g11);                   \
        const float ee11 = P11 + (gp10 * g10 + gp11 * g11);                   \
        mbc0 += gam00 * bb0 + gam01 * bb1;                                    \
        mbc1 += gam10 * bb0 + gam11 * bb1;                                    \
        const float u00 = gam00 * ee00 + gam01 * ee01;                        \
        const float u01 = gam00 * ee01 + gam01 * ee11;                        \
        const float u10 = gam10 * ee00 + gam11 * ee01;                        \
        const float u11 = gam10 * ee01 + gam11 * ee11;                        \
        const float r00 = u00 * gam00 + u01 * gam01;                          \
        const float r01 = u00 * gam10 + u01 * gam11;                          \
        const float r11 = u10 * gam10 + u11 * gam11;                          \
        if (SGNPLUS) { me00 += r00; me01 += r01; me11 += r11; }               \
        else         { me00 -= r00; me01 -= r01; me11 -= r11; }               \
        const float ng00 = gam00 * g00 + gam01 * g10;                         \
        const float ng01 = gam00 * g01 + gam01 * g11;                         \
        const float ng10 = gam10 * g00 + gam11 * g10;                         \
        const float ng11 = gam10 * g01 + gam11 * g11;                         \
        gam00 = ng00; gam01 = ng01; gam10 = ng10; gam11 = ng11;               \
    }

// one 16-step phase computed from LDS buffer BSEL; DA = this phase's dt regs.
// dtc for step tt=t0+j is dtv[tt-1]: j==0 -> dprev (carried), else DA[j-1].
#define PHASE(BSEL, DA, T0) {                                                 \
    const bool wr = (T0) >= s;   /* phase-uniform: t0,s multiples of 16 */    \
    _Pragma("unroll")                                                         \
    for (int j = 0; j < 16; ++j) {                                            \
        const int tt = (T0) + j;                                              \
        const float yv  = ylds[BSEL][j][tx];                                  \
        const float rvv = rlds[BSEL][j][tx];                                  \
        const float dre = (j == 0) ? dprev : F4E(DA, ((j + 3) & 15));         \
        const float dtc = (tt == 0) ? 0.f : dre;  /* exact A=I,Q=0 at t=0 */  \
        const float ldt = dtc * lam;                                          \
        const float ee  = __expf(-ldt);                                       \
        const float a11 = ee * (ldt + 1.f);                                   \
        const float a12 = ee * dtc;                                           \
        const float a21 = -ee * lam * ldt;                                    \
        const float a22 = ee * (1.f - ldt);                                   \
        const float q00 = pv0 - (a11 * a11 * pv0 + a12 * a12 * pv1);          \
        const float q01 = -(a11 * a21 * pv0 + a12 * a22 * pv1);               \
        const float q11 = pv1 - (a21 * a21 * pv0 + a22 * a22 * pv1);          \
        const float mp0 = a11 * m0 + a12 * m1;                                \
        const float mp1 = a21 * m0 + a22 * m1;                                \
        const float ap00 = a11 * P00 + a12 * P01;                             \
        const float ap01 = a11 * P01 + a12 * P11;                             \
        const float ap10 = a21 * P00 + a22 * P01;                             \
        const float ap11 = a21 * P01 + a22 * P11;                             \
        const float pp00 = ap00 * a11 + ap01 * a12 + q00;                     \
        const float pp01 = ap00 * a21 + ap01 * a22 + q01;                     \
        const float pp11 = ap10 * a21 + ap11 * a22 + q11;                     \
        if (tt > s) MAPCOMPOSE((j & 1) != 0);   /* step t = tt-1 */           \
        const float ssv  = pp00 + rvv;                                        \
        const float d    = yv - mp0;                                          \
        const float sinv = __builtin_amdgcn_rcpf(ssv + JIT);                  \
        const float W0 = pp00 * sinv;                                         \
        const float W1 = pp01 * sinv;                                         \
        m0 = mp0 + W0 * d;                                                    \
        m1 = mp1 + W1 * d;                                                    \
        P00 = pp00 - W0 * pp00;                                               \
        P01 = pp01 - W0 * pp01;                                               \
        P11 = pp11 - W1 * pp01;                                               \
        if (wr) {                                                             \
            acc += -0.5f * (d * d * __builtin_amdgcn_rcpf(ssv)                \
                            + __logf(ssv) + C_LOG2PI);                        \
            if ((j & 1) == 0) { bm0 = m0; bm1 = m1; }   /* tt even */         \
            else mo4[tt >> 1] = make_float4(bm0, bm1, m0, m1);                \
            Po[tt] = make_float4(P00, P01, P01, P11);                         \
        }                                                                     \
    }                                                                         \
    dprev = DA[3].w;   /* dtv[t0+15] feeds next phase's j=0 */                \
}

    // software pipeline over phase PAIRS (nph always even):
    //   buf0 <- even phases (regs A), buf1 <- odd phases (regs B)
    PLOAD(YaA, RaA, DaA, u0);
    PWRITE(0, YaA, RaA);
    for (int ph = 0; ph < nph; ph += 2) {
        const int t0 = u0 + (ph << 4);
        __syncthreads();                          // buf0(tile ph) visible
        if (ph + 1 < nph) PLOAD(YaB, RaB, DaB, t0 + 16);   // overlaps compute
        PHASE(0, DaA, t0);
        PWRITE(1, YaB, RaB);                      // waits staging loads only
        __syncthreads();                          // buf1(tile ph+1) visible
        if (ph + 2 < nph) PLOAD(YaA, RaA, DaA, t0 + 32);
        PHASE(1, DaB, t0 + 16);
        if (ph + 2 < nph) PWRITE(0, YaA, RaA);
    }

    // epilogue: final map element, step t = e-1 (uses dt[e-1] and the
    // filtered state at e-1 now in registers). Last chunk has no step T-1.
    if (chunk != NCHUNK - 1) {
        const float dtc = dtv[e - 1];
        const float ldt = dtc * lam;
        const float ee  = __expf(-ldt);
        const float a11 = ee * (ldt + 1.f);
        const float a12 = ee * dtc;
        const float a21 = -ee * lam * ldt;
        const float a22 = ee * (1.f - ldt);
        const float q00 = pv0 - (a11 * a11 * pv0 + a12 * a12 * pv1);
        const float q01 = -(a11 * a21 * pv0 + a12 * a22 * pv1);
        const float q11 = pv1 - (a21 * a21 * pv0 + a22 * a22 * pv1);
        const float mp0 = a11 * m0 + a12 * m1;
        const float mp1 = a21 * m0 + a22 * m1;
        const float ap00 = a11 * P00 + a12 * P01;
        const float ap01 = a11 * P01 + a12 * P11;
        const float ap10 = a21 * P00 + a22 * P01;
        const float ap11 = a21 * P01 + a22 * P11;
        const float pp00 = ap00 * a11 + ap01 * a12 + q00;
        const float pp01 = ap00 * a21 + ap01 * a22 + q01;
        const float pp11 = ap10 * a21 + ap11 * a22 + q11;
        // compose count so far = 30 (even) -> '+'
        MAPCOMPOSE(1);
    }
    {
        const size_t mix = (size_t)chunk * NCHAIN + chain;   // coalesced
        g4w[mix] = make_float4(gam00, gam01, gam10, gam11);
        b2w[mix] = make_float2(mbc0, mbc1);
        e4w[mix] = make_float4(me00, me01, me11, 0.f);
    }

    for (int mask = 8; mask >= 1; mask >>= 1)
        acc += __shfl_xor(acc, mask, 16);
    if ((tx & 15) == 0)
        atomicAdd(&slp[v], acc);
}

// ---------------------------------------------------------------------------
// Per-chain suffix scan of the chunk maps (right to left), starting from the
// exact terminal state (mf,Pf at T-1). Emits each chunk's exact incoming
// boundary state. 512 threads total; loads batched for MLP. Chunk 255 has 31
// composed steps -> its X-term sign is -1; all others (32 steps) +1.
// ---------------------------------------------------------------------------
__global__ void __launch_bounds__(256) kf_scan(
    const float* __restrict__ m_fs,
    const float* __restrict__ P_fs,
    const float4* __restrict__ g4w,
    const float2* __restrict__ b2w,
    const float4* __restrict__ e4w,
    float2* __restrict__ xmw,    // (NCHUNK, NCHAIN) incoming mean
    float4* __restrict__ xPw)    // (NCHUNK, NCHAIN) incoming cov (sym)
{
    const int c = blockIdx.x * 256 + threadIdx.x;   // chain 0..511
    const float* mt = m_fs + ((size_t)c * TT + (TT - 1)) * 2;
    const float* Pt = P_fs + ((size_t)c * TT + (TT - 1)) * 4;
    float xm0 = mt[0], xm1 = mt[1];
    float XP00 = Pt[0], XP01 = Pt[1], XP11 = Pt[3];

    float4 Gb[SB]; float2 Bb[SB]; float4 Eb[SB];
    for (int kb = NCHUNK - 1; kb >= 0; kb -= SB) {
#pragma unroll
        for (int j = 0; j < SB; ++j) {
            const size_t ix = (size_t)(kb - j) * NCHAIN + c;
            Gb[j] = g4w[ix]; Bb[j] = b2w[ix]; Eb[j] = e4w[ix];
        }
        __builtin_amdgcn_sched_barrier(0);
#pragma unroll
        for (int j = 0; j < SB; ++j) {
            const int k = kb - j;
            const size_t ix = (size_t)k * NCHAIN + c;
            xmw[ix] = make_float2(xm0, xm1);
            xPw[ix] = make_float4(XP00, XP01, XP11, 0.f);
            const float4 G = Gb[j]; const float2 B = Bb[j]; const float4 E = Eb[j];
            const float nm0 = B.x + G.x * xm0 + G.y * xm1;
            const float nm1 = B.y + G.z * xm0 + G.w * xm1;
            const float u00 = G.x * XP00 + G.y * XP01;
            const float u01 = G.x * XP01 + G.y * XP11;
            const float u10 = G.z * XP00 + G.w * XP01;
            const float u11 = G.z * XP01 + G.w * XP11;
            const float r00 = u00 * G.x + u01 * G.y;
            const float r01 = u00 * G.z + u01 * G.w;
            const float r11 = u10 * G.z + u11 * G.w;
            xm0 = nm0; xm1 = nm1;
            if (k == NCHUNK - 1) { XP00 = E.x - r00; XP01 = E.y - r01; XP11 = E.z - r11; }
            else                 { XP00 = E.x + r00; XP01 = E.y + r01; XP11 = E.z + r11; }
        }
    }
}

// ---------------------------------------------------------------------------
// Backward RTS smoother, apply-only: exact incoming state from the scan,
// 32 steps/thread, data read ONCE (no warm-up). Double-buffered 8-step
// batches with sched_barrier-pinned load issue.  (round-2 verbatim)
// ---------------------------------------------------------------------------
__global__ void __launch_bounds__(256)
__attribute__((amdgpu_waves_per_eu(2, 2)))
kf_bwd(
    const float* __restrict__ dt,
    const float* __restrict__ ls,
    const float* __restrict__ var,
    const float* __restrict__ m_fs,
    const float* __restrict__ P_fs,
    const float2* __restrict__ xmw,
    const float4* __restrict__ xPw,
    float* __restrict__ mZ,   // (V,L,T)
    float* __restrict__ PZ)   // (V,L,T)
{
    const int tid   = blockIdx.x * 256 + threadIdx.x;
    const int chain = tid & (NCHAIN - 1);
    const int k     = tid / NCHAIN;     // uniform per block
    const int v = chain >> 4;
    const int l = chain & 15;

    const float lam = 1.7320508075688772f / ls[l];
    const float v0  = var[l];
    const float v1  = v0 * lam * lam;

    const int s = k * CHUNK;
    const int e = s + CHUNK;

    const float* dtv = dt + (size_t)v * (TT - 1);
    const float2* mi  = (const float2*)(m_fs + (size_t)chain * TT * 2);
    const float4* mi4 = (const float4*)(m_fs + (size_t)chain * TT * 2);
    const float4* Pi  = (const float4*)(P_fs + (size_t)chain * TT * 4);
    float* mo = mZ + (size_t)chain * TT;
    float* Po = PZ + (size_t)chain * TT;

    const size_t mix = (size_t)k * NCHAIN + chain;   // coalesced
    const float2 x2 = xmw[mix];
    const float4 xq = xPw[mix];
    float ms0 = x2.x, ms1 = x2.y;
    float Ps00 = xq.x, Ps01 = xq.y, Ps11 = xq.z;

    // one smoother step; updates carry (ms*, Ps*)
    auto step = [&](float dtc, float mf0, float mf1,
                    float Pf00, float Pf01, float Pf11) {
        const float ldt = dtc * lam;
        const float ee  = __expf(-ldt);
        const float a11 = ee * (ldt + 1.f);
        const float a12 = ee * dtc;
        const float a21 = -ee * lam * ldt;
        const float a22 = ee * (1.f - ldt);
        const float q00 = v0 - (a11 * a11 * v0 + a12 * a12 * v1);
        const float q01 = -(a11 * a21 * v0 + a12 * a22 * v1);
        const float q11 = v1 - (a21 * a21 * v0 + a22 * a22 * v1);

        const float mp0 = a11 * mf0 + a12 * mf1;
        const float mp1 = a21 * mf0 + a22 * mf1;
        const float ap00 = a11 * Pf00 + a12 * Pf01;   // A @ P_f (symmetric)
        const float ap01 = a11 * Pf01 + a12 * Pf11;
        const float ap10 = a21 * Pf00 + a22 * Pf01;
        const float ap11 = a21 * Pf01 + a22 * Pf11;
        const float pp00 = ap00 * a11 + ap01 * a12 + q00;
        const float pp01 = ap00 * a21 + ap01 * a22 + q01;
        const float pp11 = ap10 * a21 + ap11 * a22 + q11;

        // G = (solve(P_p + jI, A_Pf))^T via 2x2 adjugate
        const float M00 = pp00 + JIT, M11 = pp11 + JIT;
        const float dinv = __builtin_amdgcn_rcpf(M00 * M11 - pp01 * pp01);
        const float G00 = (M11 * ap00 - pp01 * ap10) * dinv;
        const float G01 = (-pp01 * ap00 + M00 * ap10) * dinv;
        const float G10 = (M11 * ap01 - pp01 * ap11) * dinv;
        const float G11 = (-pp01 * ap01 + M00 * ap11) * dinv;

        const float dm0 = ms0 - mp0, dm1 = ms1 - mp1;
        const float nms0 = mf0 + G00 * dm0 + G01 * dm1;
        const float nms1 = mf1 + G10 * dm0 + G11 * dm1;
        const float D00 = Ps00 - pp00, D01 = Ps01 - pp01, D11 = Ps11 - pp11;
        const float gd00 = G00 * D00 + G01 * D01;
        const float gd01 = G00 * D01 + G01 * D11;
        const float gd10 = G10 * D00 + G11 * D01;
        const float gd11 = G10 * D01 + G11 * D11;
        ms0 = nms0; ms1 = nms1;
        Ps00 = Pf00 - (gd00 * G00 + gd01 * G01);
        Ps01 = Pf01 - (gd00 * G10 + gd01 * G11);
        Ps11 = Pf11 - (gd10 * G10 + gd11 * G11);
    };

    int t;
    if (k == NCHUNK - 1) {
        mo[TT - 1] = ms0;       // terminal output is the incoming state
        Po[TT - 1] = Ps00;
        t = TT - 2;             // 8190
    } else {
        t = e - 1;              // ≡ 31 (mod 32) -> no peel
    }

    // peel until t ≡ 7 (mod 8); scalar stores (only last chunk: 7 steps)
    for (; t >= s && (t & 7) != 7; --t) {
        const float2 mf2 = mi[t];
        const float4 Pf4 = Pi[t];
        step(dtv[t], mf2.x, mf2.y, Pf4.x, Pf4.y, Pf4.w);
        mo[t] = ms0; Po[t] = Ps00;
    }

    float b0m = 0.f, b1m = 0.f, b2m = 0.f, b3m = 0.f;
    float b0P = 0.f, b1P = 0.f, b2P = 0.f, b3P = 0.f;

    float4 Ma[BB / 2], Pa[BB]; float Da[BB];
    float4 Mb[BB / 2], Pb[BB]; float Db[BB];

// batch covers tt = tb-7 .. tb, tb ≡ 7 (mod 8).
// m loaded as 4 aligned float4 (2 timesteps each).
#define BLOAD(M, P, D, tb) {                                                  \
    const int ib_ = ((tb) - 7) >> 1;                                          \
    _Pragma("unroll")                                                         \
    for (int j = 0; j < BB / 2; ++j) M[j] = mi4[ib_ + j];                     \
    _Pragma("unroll")                                                         \
    for (int j = 0; j < BB; ++j) {                                            \
        const int tt_ = (tb) - j;                                             \
        P[j] = Pi[tt_];                                                       \
        D[j] = dtv[tt_];                                                      \
    }                                                                         \
}

#define BCOMP(M, P, D, tb) {                                                  \
    _Pragma("unroll")                                                         \
    for (int jj = 0; jj < BB; ++jj) {                                         \
        const int tt_ = (tb) - jj;                                            \
        const int k_  = 7 - jj;          /* index within ascending batch */   \
        const float mf0_ = (k_ & 1) ? M[k_ >> 1].z : M[k_ >> 1].x;            \
        const float mf1_ = (k_ & 1) ? M[k_ >> 1].w : M[k_ >> 1].y;            \
        step(D[jj], mf0_, mf1_, P[jj].x, P[jj].y, P[jj].w);                   \
        const int slot_ = k_ & 3;        /* == tt_ & 3, compile-time */       \
        if (slot_ == 3)      { b3m = ms0; b3P = Ps00; }                       \
        else if (slot_ == 2) { b2m = ms0; b2P = Ps00; }                       \
        else if (slot_ == 1) { b1m = ms0; b1P = Ps00; }                       \
        else {                                                                \
            b0m = ms0; b0P = Ps00;                                            \
            {                            /* tt_ & 3 == 0, 16B-aligned */      \
                *(float4*)(mo + tt_) = make_float4(b0m, b1m, b2m, b3m);       \
                *(float4*)(Po + tt_) = make_float4(b0P, b1P, b2P, b3P);       \
            }                                                                 \
        }                                                                     \
    }                                                                         \
}

    // software pipeline over 8-step batches; odd batch counts get a tail
    int nb = (t - s + 1) >> 3;      // 4 (k<255) or 3 (k==255)
    if (nb > 0) {
        BLOAD(Ma, Pa, Da, t);
        __builtin_amdgcn_sched_barrier(0);
        for (; nb >= 2; nb -= 2) {
            BLOAD(Mb, Pb, Db, t - BB);
            __builtin_amdgcn_sched_barrier(0);
            BCOMP(Ma, Pa, Da, t);
            t -= BB;
            if (nb > 2) {
                BLOAD(Ma, Pa, Da, t - BB);
                __builtin_amdgcn_sched_barrier(0);
            }
            BCOMP(Mb, Pb, Db, t);
            t -= BB;
        }
        if (nb == 1) BCOMP(Ma, Pa, Da, t);
    }
}

extern "C" void kernel_launch(void* const* d_in, const int* in_sizes, int n_in,
                              void* d_out, int out_size, void* d_ws, size_t ws_size,
                              hipStream_t stream) {
    const float* dt  = (const float*)d_in[0];
    const float* y   = (const float*)d_in[1];
    const float* rv  = (const float*)d_in[2];
    const float* ls  = (const float*)d_in[3];
    const float* var = (const float*)d_in[4];

    float* out  = (float*)d_out;
    float* m_fs = out;                                    // V*L*T*2
    float* P_fs = m_fs + (size_t)NCHAIN * TT * 2;         // V*L*T*4
    float* mZ   = P_fs + (size_t)NCHAIN * TT * 4;         // V*L*T
    float* PZ   = mZ + (size_t)NCHAIN * TT;               // V*L*T
    float* slp  = PZ + (size_t)NCHAIN * TT;               // V

    // workspace: chunk maps + scan output, 64 B per (chunk,chain) = 8 MiB
    float4* g4w = (float4*)d_ws;
    float4* e4w = g4w + (size_t)NCHUNK * NCHAIN;
    float4* xPw = e4w + (size_t)NCHUNK * NCHAIN;
    float2* b2w = (float2*)(xPw + (size_t)NCHUNK * NCHAIN);
    float2* xmw = b2w + (size_t)NCHUNK * NCHAIN;

    hipMemsetAsync(slp, 0, TV * sizeof(float), stream);   // graph-capture safe

    const int ntask = NCHAIN * NCHUNK;                    // 131072 threads
    kf_fwd<<<ntask / 256, 256, 0, stream>>>(dt, y, rv, ls, var, m_fs, P_fs, slp,
                                            g4w, b2w, e4w);
    kf_scan<<<NCHAIN / 256, 256, 0, stream>>>(m_fs, P_fs, g4w, b2w, e4w, xmw, xPw);
    kf_bwd<<<ntask / 256, 256, 0, stream>>>(dt, ls, var, m_fs, P_fs, xmw, xPw, mZ, PZ);
}